// Round 7
// baseline (1558.345 us; speedup 1.0000x reference)
//
#include <hip/hip_runtime.h>
#include <math.h>

#define Lr    32
#define Hh    128
#define NCHW  9                    // chunks per wave (72 rows per lane-half, 8 rows/chunk)
#define CHB   1024                 // chunk bytes: 64 lanes x 16 B (8 fp16 weights)
#define WWAVE (NCHW * CHB)         // 9216 B weights per wave per cell
#define WCELL (4 * WWAVE)          // 36864 B
#define CELLB (WCELL + 4 * 512)    // + per-wave b1dup/wfdup fp32 (512 B each) = 38912
#define NEPS  1e-8f

typedef _Float16 half2_t __attribute__((ext_vector_type(2)));

#define AS1 __attribute__((address_space(1)))
#define AS3 __attribute__((address_space(3)))

__device__ __forceinline__ void dma16(const void* g, void* l) {
    __builtin_amdgcn_global_load_lds((const AS1 unsigned int*)g, (AS3 unsigned int*)l, 16, 0, 0);
}
__device__ __forceinline__ void dma4(const void* g, void* l) {
    __builtin_amdgcn_global_load_lds((const AS1 unsigned int*)g, (AS3 unsigned int*)l, 4, 0, 0);
}
// Barrier draining LDS only — in-flight DMAs (vmcnt) survive across it.
__device__ __forceinline__ void bar_lds() {
    asm volatile("s_waitcnt lgkmcnt(0)\n\ts_barrier" ::: "memory");
}
#define WAITVM6 asm volatile("s_waitcnt vmcnt(6)" ::: "memory")
#define WAITVM5 asm volatile("s_waitcnt vmcnt(5)" ::: "memory")
#define WAITLG0 asm volatile("s_waitcnt lgkmcnt(0)" ::: "memory")

__device__ __forceinline__ int cell_of(int s) {
    const int i = s >> 5, jj = s & 31;
    return i * Lr + ((i & 1) ? (Lr - 1 - jj) : jj);
}

__device__ __forceinline__ float fdot2h(unsigned int a, unsigned int b, float c) {
#if __has_builtin(__builtin_amdgcn_fdot2)
    return __builtin_amdgcn_fdot2(__builtin_bit_cast(half2_t, a),
                                  __builtin_bit_cast(half2_t, b), c, false);
#else
    const half2_t x = __builtin_bit_cast(half2_t, a);
    const half2_t y = __builtin_bit_cast(half2_t, b);
    return c + (float)x.x * (float)y.x + (float)x.y * (float)y.y;
#endif
}

// Blob layout per step s (visitation order):
//   wave w (4) | chunk c (9): 64 lanes x 16 B; lane l's 8 fp16 = W[k][r],
//   k = 32w + (l>>1), r = 72*(l&1) + 8c + i (i<8), zero if r>=130.
//   Then per wave: b1dup fp32[64] (lane-duplicated b1[k]), wfdup fp32[64].
__global__ __launch_bounds__(256)
void prep_blob(const float* __restrict__ W1, const float* __restrict__ b1,
               const float* __restrict__ Wf, unsigned char* __restrict__ blob) {
    const int s = blockIdx.x;
    const int cell = cell_of(s);
    const float* wsrc = W1 + (size_t)cell * (Hh * 130);
    unsigned char* dst = blob + (size_t)s * CELLB;
    for (int idx = threadIdx.x; idx < 4 * NCHW * 64; idx += 256) {
        const int w = idx / (NCHW * 64), rem = idx % (NCHW * 64);
        const int c = rem >> 6, l = rem & 63;
        const int k = 32 * w + (l >> 1);
        const int rbase = 72 * (l & 1) + 8 * c;
        _Float16* o = (_Float16*)(dst + (size_t)w * WWAVE + c * CHB + l * 16);
#pragma unroll
        for (int i = 0; i < 8; ++i) {
            const int r = rbase + i;
            o[i] = (r < 130) ? (_Float16)wsrc[k * 130 + r] : (_Float16)0.f;
        }
    }
    for (int idx = threadIdx.x; idx < 256; idx += 256) {
        const int w = idx >> 6, l = idx & 63;
        const int k = 32 * w + (l >> 1);
        float* bo = (float*)(dst + WCELL + w * 512);
        bo[l]      = b1[cell * Hh + k];
        bo[64 + l] = Wf[cell * Hh + k];
    }
}

// 512 blocks x 1 batch element (2 blocks/CU). k-split: lane pair (2l,2l+1) of
// wave w owns output k = 32w+l; the pair splits the 130-row dot (72/72 padded).
// No cross-wave reduction -> ONE lgkm-only barrier per cell (inp handoff).
// Weights/bias for cell s+1 DMA'd while cell s computes (vmcnt discipline).
__global__ __launch_bounds__(256, 2)
void rnn2d(const float* __restrict__ samples, const unsigned char* __restrict__ blob,
           const float* __restrict__ bfv, float* __restrict__ out)
{
    __shared__ __align__(16) unsigned char wreg[WCELL];  // 36 KB fp16 strips
    __shared__ float bw[4][2][2][64];          // [wave][parity][b1|wf][lane] 4 KB
    __shared__ float hv[Lr][Hh];               // 16 KB vertical hidden (wave-private k's)
    __shared__ __align__(16) _Float16 inph[2][144];  // double-buffered fp16 input vec
    __shared__ float smp[Lr * Lr];             // 4 KB samples
    __shared__ float bfs[Lr * Lr];             // 4 KB head bias
    __shared__ float fpart[2][4];              // per-wave head-dot partials (dbuf)

    const int t  = threadIdx.x;
    const int kp = t & 63;
    const int w  = t >> 6;
    const int b  = blockIdx.x;
    const int kk = 32 * w + (kp >> 1);         // owned output k

    for (int idx = t; idx < Lr * Hh; idx += 256) ((float*)hv)[idx] = 0.f;
    for (int idx = t; idx < 2 * 144; idx += 256)
        ((_Float16*)inph)[idx] = (idx == 1) ? (_Float16)2.f : (_Float16)0.f;
    for (int idx = t; idx < Lr * Lr; idx += 256) {
        smp[idx] = samples[(size_t)b * (Lr * Lr) + idx];
        bfs[idx] = bfv[idx];
    }
    float lp = 0.f;
    __syncthreads();   // full drain — vmcnt bookkeeping starts at 0

    unsigned char* lbase = wreg + w * WWAVE;

#define ISSUE_A(SN)                                                            \
    {                                                                          \
        const unsigned char* gs = blob + (size_t)(SN) * CELLB                  \
                                + (size_t)w * WWAVE + kp * 16;                 \
        dma16(gs,           lbase);                                            \
        dma16(gs + CHB,     lbase + CHB);                                      \
        dma16(gs + 2 * CHB, lbase + 2 * CHB);                                  \
        dma16(gs + 3 * CHB, lbase + 3 * CHB);                                  \
        dma16(gs + 4 * CHB, lbase + 4 * CHB);                                  \
    }
#define ISSUE_B(SN)                                                            \
    {                                                                          \
        const unsigned char* gs = blob + (size_t)(SN) * CELLB                  \
                                + (size_t)w * WWAVE + kp * 16;                 \
        dma16(gs + 5 * CHB, lbase + 5 * CHB);                                  \
        dma16(gs + 6 * CHB, lbase + 6 * CHB);                                  \
        dma16(gs + 7 * CHB, lbase + 7 * CHB);                                  \
        dma16(gs + 8 * CHB, lbase + 8 * CHB);                                  \
        const unsigned char* gb = blob + (size_t)(SN) * CELLB + WCELL          \
                                + w * 512 + kp * 4;                            \
        dma4(gb,       &bw[w][(SN) & 1][0][0]);                                \
        dma4(gb + 256, &bw[w][(SN) & 1][1][0]);                                \
    }
#define CONSUME(C0, C1)                                                        \
    _Pragma("unroll")                                                          \
    for (int c_ = (C0); c_ < (C1); ++c_) {                                     \
        const uint4 wv = *(const uint4*)(lbase + c_ * CHB + kp * 16);          \
        const uint4 iv = ipb[c_];                                              \
        float& ac = (c_ & 1) ? acc1 : acc0;                                    \
        ac = fdot2h(wv.x, iv.x, ac);                                           \
        ac = fdot2h(wv.y, iv.y, ac);                                           \
        ac = fdot2h(wv.z, iv.z, ac);                                           \
        ac = fdot2h(wv.w, iv.w, ac);                                           \
    }
#define LPFIN(CC, P)                                                           \
    {                                                                          \
        const float z_ = fpart[P][0] + fpart[P][1] + fpart[P][2] + fpart[P][3] \
                       + bfs[CC];                                              \
        const float xhat_ = 1.f / (1.f + __expf(-z_));                         \
        const float mc_   = smp[CC];                                           \
        lp += __logf(xhat_ + NEPS) * mc_ + __logf(1.f - xhat_ + NEPS) * (1.f - mc_); \
    }

    ISSUE_A(0);   // 5 in flight
    ISSUE_B(0);   // 11 in flight — steady-state invariant at loop top
    for (int s = 0; s < Lr * Lr; ++s) {
        const int i_ = s >> 5, j_ = s & 31;
        const int c_col = (i_ & 1) ? (Lr - 1 - j_) : j_;
        const int sn = (s < Lr * Lr - 1) ? s + 1 : s;

        // deferred lp tail for cell s-1 (lane 128 only; LDS-only reads)
        if (t == 128 && s > 0) { LPFIN(cell_of(s - 1), (s - 1) & 1) }

        const uint4* ipb = (const uint4*)((const unsigned char*)inph
                         + (s & 1) * 288 + (kp & 1) * 144);
        float acc0 = 0.f, acc1 = 0.f;
        WAITVM6;                    // drain A_s (5); B_s (6) stays in flight
        CONSUME(0, 5);
        WAITLG0; ISSUE_A(sn);       // -> 11 in flight
        WAITVM5;                    // drain B_s (6); A_{s+1} (5) stays
        CONSUME(5, 9);

        // epilogue: each lane pair finishes its k
        float accs = acc0 + acc1;
        accs += __shfl_xor(accs, 1);
        const float pre = accs + 2.f * bw[w][s & 1][0][kp];
        const float e2  = __expf(2.f * pre);
        const float h_  = 1.f - 2.f / (e2 + 1.f);   // tanh(pre)

        if (s + 1 < Lr * Lr) {
            const int sn_ = s + 1, in_ = sn_ >> 5, jn_ = sn_ & 31;
            const int cn_ = (in_ & 1) ? (Lr - 1 - jn_) : jn_;
            if ((kp & 1) == 0) {
                const float hvn_ = (cn_ == c_col) ? h_ : hv[cn_][kk];
                inph[(sn_ & 1)][kk + 2] = (_Float16)(((jn_ == 0) ? 0.f : h_) + hvn_);
                hv[c_col][kk] = h_;
            }
            if (t == 0) {
                const float xh_ = (jn_ == 0) ? 0.f : smp[i_ * Lr + c_col];
                const float xv_ = (in_ == 0) ? 0.f : smp[(in_ - 1) * Lr + cn_];
                inph[(sn_ & 1)][0] = (_Float16)(xh_ + xv_);
                inph[(sn_ & 1)][1] = (_Float16)(2.f - xh_ - xv_);
            }
        }
        // head partial: even lanes contribute h*wf, wave-reduce, one slot/wave
        float f_ = (kp & 1) ? 0.f : h_ * bw[w][s & 1][1][kp];
        f_ += __shfl_xor(f_, 1);
        f_ += __shfl_xor(f_, 2);
        f_ += __shfl_xor(f_, 4);
        f_ += __shfl_xor(f_, 8);
        f_ += __shfl_xor(f_, 16);
        f_ += __shfl_xor(f_, 32);
        if (kp == 0) fpart[s & 1][w] = f_;

        WAITLG0; ISSUE_B(sn);       // -> 11 in flight across the barrier
        bar_lds();                  // lgkm-only: DMAs keep flying
    }
    asm volatile("s_waitcnt vmcnt(0)" ::: "memory");   // drain dangling DMAs
    if (t == 128) {
        LPFIN(cell_of(Lr * Lr - 1), (Lr * Lr - 1) & 1)
        out[b] = lp;
    }
#undef ISSUE_A
#undef ISSUE_B
#undef CONSUME
#undef LPFIN
}

extern "C" void kernel_launch(void* const* d_in, const int* in_sizes, int n_in,
                              void* d_out, int out_size, void* d_ws, size_t ws_size,
                              hipStream_t stream) {
    const float* samples = (const float*)d_in[0];
    const float* W1      = (const float*)d_in[1];
    const float* b1      = (const float*)d_in[2];
    const float* Wf      = (const float*)d_in[3];
    const float* bf      = (const float*)d_in[4];
    float* outp = (float*)d_out;
    unsigned char* blob = (unsigned char*)d_ws;   // 1024 * 38912 = 39.8 MB

    prep_blob<<<1024, 256, 0, stream>>>(W1, b1, Wf, blob);
    rnn2d<<<512, 256, 0, stream>>>(samples, blob, bf, outp);
}